// Round 10
// baseline (324.486 us; speedup 1.0000x reference)
//
#include <hip/hip_runtime.h>

namespace {

constexpr int K     = 6;
constexpr int KK    = 36;   // K*K
constexpr int DF    = 8;    // D_FEAT
constexpr int DLAT  = 16;
constexpr int NS    = 5;
constexpr int B     = 131072;
constexpr int M     = NS * B;
constexpr float EPS = 1e-20f;

typedef float f32x4 __attribute__((ext_vector_type(4)));  // native vec for NT builtins

// grid = 2560 blocks of 256. blockIdx -> (s = bid%5, bc = bid/5) so the 5
// blocks sharing one b-range are dispatched back-to-back (latent/seq stay
// L3-hot) while each wave's 64 noise/out rows are contiguous (coalescing).
// One thread per (s,b). Noise is staged wave-cooperatively through LDS:
// coalesced 1KB/instr global loads issued FIRST, then the noise-independent
// matvec/masknet/exp runs under the HBM latency, then LDS exchange.
__global__ __launch_bounds__(256, 4) void fused_kernel(
    const float* __restrict__ latent,
    const float* __restrict__ seq,
    const float* __restrict__ noise,
    const float* __restrict__ W_sink,
    const float* __restrict__ b_sink,
    const float* __restrict__ W_mask,
    const float* __restrict__ b_mask,
    float* __restrict__ out,        // [NS*B][48]
    float* __restrict__ stopping)   // [B][6]
{
    __shared__ f32x4 nbuf[4][64 * 9];   // per-wave 9216 B noise slab

    const int bid = blockIdx.x;
    const int s   = bid % NS;            // sample
    const int bc  = bid / NS;            // b-chunk (0..511)
    const int t   = threadIdx.x;
    const int w   = t >> 6;              // wave in block
    const int l   = t & 63;              // lane
    const int b   = bc * 256 + t;
    const size_t row = (size_t)s * B + b;

    // ---- issue wave-coalesced noise loads (64 rows x 144 B, contiguous) ----
    const f32x4* nsrc = reinterpret_cast<const f32x4*>(noise)
                      + ((size_t)s * B + (size_t)bc * 256 + (size_t)w * 64) * 9;
    f32x4 stage[9];
    #pragma unroll
    for (int j = 0; j < 9; ++j)
        stage[j] = __builtin_nontemporal_load(&nsrc[l + 64 * j]);

    // ---- noise-independent work overlaps the HBM latency ----
    float lat[DLAT];
    {
        const float4* lat4 = reinterpret_cast<const float4*>(latent + (size_t)b * DLAT);
        #pragma unroll
        for (int k2 = 0; k2 < 4; ++k2) {
            float4 v = lat4[k2];
            lat[k2*4+0] = v.x; lat[k2*4+1] = v.y; lat[k2*4+2] = v.z; lat[k2*4+3] = v.w;
        }
    }

    // sinknet matvec; W/b indices wave-uniform -> scalar loads
    float ela[KK];
    #pragma unroll
    for (int i = 0; i < KK; ++i) ela[i] = b_sink[i];
    #pragma unroll
    for (int k2 = 0; k2 < DLAT; ++k2) {
        const float lv = lat[k2];
        #pragma unroll
        for (int i = 0; i < KK; ++i)
            ela[i] = fmaf(lv, W_sink[k2*KK + i], ela[i]);
    }

    if (s == 0) {   // masknet once per b (only the s==0 block does it)
        float v[K];
        #pragma unroll
        for (int i = 0; i < K; ++i) v[i] = b_mask[i];
        #pragma unroll
        for (int k2 = 0; k2 < DLAT; ++k2) {
            const float lv = lat[k2];
            #pragma unroll
            for (int i = 0; i < K; ++i)
                v[i] = fmaf(lv, W_mask[k2*K + i], v[i]);
        }
        float mx = v[0];
        #pragma unroll
        for (int i = 1; i < K; ++i) mx = fmaxf(mx, v[i]);
        float sum = 0.f;
        #pragma unroll
        for (int i = 0; i < K; ++i) { v[i] = __expf(v[i] - mx); sum += v[i]; }
        const float inv = __builtin_amdgcn_rcpf(sum);
        float2* o2 = reinterpret_cast<float2*>(stopping + (size_t)b * K);
        o2[0] = make_float2(v[0]*inv, v[1]*inv);
        o2[1] = make_float2(v[2]*inv, v[3]*inv);
        o2[2] = make_float2(v[4]*inv, v[5]*inv);
    }

    // exp(log_alpha) — still noise-independent
    #pragma unroll
    for (int i = 0; i < KK; ++i) ela[i] = __expf(ela[i]);

    // ---- LDS exchange: write staged slab, read own row ----
    #pragma unroll
    for (int j = 0; j < 9; ++j)
        nbuf[w][l + 64 * j] = stage[j];
    asm volatile("" ::: "memory");   // keep compiler from reordering r/w
    f32x4 nr[9];
    #pragma unroll
    for (int j = 0; j < 9; ++j)
        nr[j] = nbuf[w][l * 9 + j];  // wave-local; DS pipe is in-order

    // ---- gumbel: p = ela * rcp(EPS - log(u+EPS))  (== exp(la + g)) ----
    float p[KK];
    #pragma unroll
    for (int j = 0; j < 9; ++j) {
        f32x4 u = nr[j];
        p[j*4+0] = ela[j*4+0] * __builtin_amdgcn_rcpf(EPS - __logf(u.x + EPS));
        p[j*4+1] = ela[j*4+1] * __builtin_amdgcn_rcpf(EPS - __logf(u.y + EPS));
        p[j*4+2] = ela[j*4+2] * __builtin_amdgcn_rcpf(EPS - __logf(u.z + EPS));
        p[j*4+3] = ela[j*4+3] * __builtin_amdgcn_rcpf(EPS - __logf(u.w + EPS));
    }

    // ---- 5 Sinkhorn iterations, exp domain (== log-domain logsumexp) ----
    #pragma unroll
    for (int it = 0; it < 5; ++it) {
        #pragma unroll
        for (int i = 0; i < K; ++i) {            // rows (axis=2)
            const float sum = ((p[i*K+0] + p[i*K+1]) + (p[i*K+2] + p[i*K+3]))
                            + (p[i*K+4] + p[i*K+5]);
            const float r = __builtin_amdgcn_rcpf(sum);
            #pragma unroll
            for (int j = 0; j < K; ++j) p[i*K+j] *= r;
        }
        #pragma unroll
        for (int j = 0; j < K; ++j) {            // cols (axis=1)
            const float sum = ((p[0*K+j] + p[1*K+j]) + (p[2*K+j] + p[3*K+j]))
                            + (p[4*K+j] + p[5*K+j]);
            const float r = __builtin_amdgcn_rcpf(sum);
            #pragma unroll
            for (int i = 0; i < K; ++i) p[i*K+j] *= r;
        }
    }

    // ---- ordered[row,i,:] = sum_j P[j,i] * seq[b,j,:]  (round-5 tail) ----
    float o[K*DF];
    #pragma unroll
    for (int i = 0; i < K*DF; ++i) o[i] = 0.f;

    const float4* s4 = reinterpret_cast<const float4*>(seq + (size_t)b * (K*DF));
    #pragma unroll
    for (int j = 0; j < K; ++j) {
        float4 a0 = s4[j*2 + 0];
        float4 a1 = s4[j*2 + 1];
        float srow[DF] = {a0.x, a0.y, a0.z, a0.w, a1.x, a1.y, a1.z, a1.w};
        #pragma unroll
        for (int i = 0; i < K; ++i) {
            const float pv = p[j*K + i];
            #pragma unroll
            for (int d = 0; d < DF; ++d)
                o[i*DF + d] = fmaf(pv, srow[d], o[i*DF + d]);
        }
    }

    f32x4* o4 = reinterpret_cast<f32x4*>(out + row * (K*DF));
    #pragma unroll
    for (int q = 0; q < 12; ++q) {
        f32x4 v;
        v.x = o[q*4+0]; v.y = o[q*4+1]; v.z = o[q*4+2]; v.w = o[q*4+3];
        __builtin_nontemporal_store(v, &o4[q]);
    }
}

} // namespace

extern "C" void kernel_launch(void* const* d_in, const int* in_sizes, int n_in,
                              void* d_out, int out_size, void* d_ws, size_t ws_size,
                              hipStream_t stream) {
    const float* latent = (const float*)d_in[0];
    const float* seq    = (const float*)d_in[1];
    const float* noise  = (const float*)d_in[2];
    const float* W_sink = (const float*)d_in[3];
    const float* b_sink = (const float*)d_in[4];
    const float* W_mask = (const float*)d_in[5];
    const float* b_mask = (const float*)d_in[6];
    float* out      = (float*)d_out;
    float* stopping = out + (size_t)M * K * DF;

    fused_kernel<<<M / 256, 256, 0, stream>>>(latent, seq, noise,
                                              W_sink, b_sink, W_mask, b_mask,
                                              out, stopping);
}

// Round 11
// 105.134 us; speedup vs baseline: 3.0864x; 3.0864x over previous
//
#include <hip/hip_runtime.h>

namespace {

constexpr int K     = 6;
constexpr int KK    = 36;   // K*K
constexpr int DF    = 8;    // D_FEAT
constexpr int DLAT  = 16;
constexpr int NS    = 5;
constexpr int B     = 131072;
constexpr int M     = NS * B;
constexpr float EPS = 1e-20f;

typedef float f32x4 __attribute__((ext_vector_type(4)));  // native vec for NT builtins

// grid = 2560 blocks of 256. blockIdx -> (s = bid%5, bc = bid/5) so the 5
// blocks sharing one b-range are dispatched back-to-back (latent/seq stay
// L3-hot) while each wave's 64 noise/out rows are contiguous (coalescing).
// One thread per (s,b). Noise is staged wave-cooperatively through LDS:
// coalesced 1KB/instr global loads issued FIRST, then the noise-independent
// matvec/masknet/exp runs under the HBM latency, then LDS exchange.
// NT loads only on the streaming noise (keeps L2/L3 for latent/seq).
// Plain cached stores for out: each 64-B line is assembled from four 16-B
// stores -> must go through L2 write-combining (NT stores gave 3x write
// amplification in round 10: 399 MB vs 133 MB ideal).
__global__ __launch_bounds__(256, 4) void fused_kernel(
    const float* __restrict__ latent,
    const float* __restrict__ seq,
    const float* __restrict__ noise,
    const float* __restrict__ W_sink,
    const float* __restrict__ b_sink,
    const float* __restrict__ W_mask,
    const float* __restrict__ b_mask,
    float* __restrict__ out,        // [NS*B][48]
    float* __restrict__ stopping)   // [B][6]
{
    __shared__ f32x4 nbuf[4][64 * 9];   // per-wave 9216 B noise slab

    const int bid = blockIdx.x;
    const int s   = bid % NS;            // sample
    const int bc  = bid / NS;            // b-chunk (0..511)
    const int t   = threadIdx.x;
    const int w   = t >> 6;              // wave in block
    const int l   = t & 63;              // lane
    const int b   = bc * 256 + t;
    const size_t row = (size_t)s * B + b;

    // ---- issue wave-coalesced noise loads (64 rows x 144 B, contiguous) ----
    const f32x4* nsrc = reinterpret_cast<const f32x4*>(noise)
                      + ((size_t)s * B + (size_t)bc * 256 + (size_t)w * 64) * 9;
    f32x4 stage[9];
    #pragma unroll
    for (int j = 0; j < 9; ++j)
        stage[j] = __builtin_nontemporal_load(&nsrc[l + 64 * j]);

    // ---- noise-independent work overlaps the HBM latency ----
    float lat[DLAT];
    {
        const float4* lat4 = reinterpret_cast<const float4*>(latent + (size_t)b * DLAT);
        #pragma unroll
        for (int k2 = 0; k2 < 4; ++k2) {
            float4 v = lat4[k2];
            lat[k2*4+0] = v.x; lat[k2*4+1] = v.y; lat[k2*4+2] = v.z; lat[k2*4+3] = v.w;
        }
    }

    // sinknet matvec; W/b indices wave-uniform -> scalar loads
    float ela[KK];
    #pragma unroll
    for (int i = 0; i < KK; ++i) ela[i] = b_sink[i];
    #pragma unroll
    for (int k2 = 0; k2 < DLAT; ++k2) {
        const float lv = lat[k2];
        #pragma unroll
        for (int i = 0; i < KK; ++i)
            ela[i] = fmaf(lv, W_sink[k2*KK + i], ela[i]);
    }

    if (s == 0) {   // masknet once per b (only the s==0 block does it)
        float v[K];
        #pragma unroll
        for (int i = 0; i < K; ++i) v[i] = b_mask[i];
        #pragma unroll
        for (int k2 = 0; k2 < DLAT; ++k2) {
            const float lv = lat[k2];
            #pragma unroll
            for (int i = 0; i < K; ++i)
                v[i] = fmaf(lv, W_mask[k2*K + i], v[i]);
        }
        float mx = v[0];
        #pragma unroll
        for (int i = 1; i < K; ++i) mx = fmaxf(mx, v[i]);
        float sum = 0.f;
        #pragma unroll
        for (int i = 0; i < K; ++i) { v[i] = __expf(v[i] - mx); sum += v[i]; }
        const float inv = __builtin_amdgcn_rcpf(sum);
        float2* o2 = reinterpret_cast<float2*>(stopping + (size_t)b * K);
        o2[0] = make_float2(v[0]*inv, v[1]*inv);
        o2[1] = make_float2(v[2]*inv, v[3]*inv);
        o2[2] = make_float2(v[4]*inv, v[5]*inv);
    }

    // exp(log_alpha) — still noise-independent
    #pragma unroll
    for (int i = 0; i < KK; ++i) ela[i] = __expf(ela[i]);

    // ---- LDS exchange: write staged slab, read own row ----
    #pragma unroll
    for (int j = 0; j < 9; ++j)
        nbuf[w][l + 64 * j] = stage[j];
    asm volatile("" ::: "memory");   // keep compiler from reordering r/w
    f32x4 nr[9];
    #pragma unroll
    for (int j = 0; j < 9; ++j)
        nr[j] = nbuf[w][l * 9 + j];  // wave-local; DS pipe is in-order

    // ---- gumbel: p = ela * rcp(EPS - log(u+EPS))  (== exp(la + g)) ----
    float p[KK];
    #pragma unroll
    for (int j = 0; j < 9; ++j) {
        f32x4 u = nr[j];
        p[j*4+0] = ela[j*4+0] * __builtin_amdgcn_rcpf(EPS - __logf(u.x + EPS));
        p[j*4+1] = ela[j*4+1] * __builtin_amdgcn_rcpf(EPS - __logf(u.y + EPS));
        p[j*4+2] = ela[j*4+2] * __builtin_amdgcn_rcpf(EPS - __logf(u.z + EPS));
        p[j*4+3] = ela[j*4+3] * __builtin_amdgcn_rcpf(EPS - __logf(u.w + EPS));
    }

    // ---- 5 Sinkhorn iterations, exp domain (== log-domain logsumexp) ----
    #pragma unroll
    for (int it = 0; it < 5; ++it) {
        #pragma unroll
        for (int i = 0; i < K; ++i) {            // rows (axis=2)
            const float sum = ((p[i*K+0] + p[i*K+1]) + (p[i*K+2] + p[i*K+3]))
                            + (p[i*K+4] + p[i*K+5]);
            const float r = __builtin_amdgcn_rcpf(sum);
            #pragma unroll
            for (int j = 0; j < K; ++j) p[i*K+j] *= r;
        }
        #pragma unroll
        for (int j = 0; j < K; ++j) {            // cols (axis=1)
            const float sum = ((p[0*K+j] + p[1*K+j]) + (p[2*K+j] + p[3*K+j]))
                            + (p[4*K+j] + p[5*K+j]);
            const float r = __builtin_amdgcn_rcpf(sum);
            #pragma unroll
            for (int i = 0; i < K; ++i) p[i*K+j] *= r;
        }
    }

    // ---- ordered[row,i,:] = sum_j P[j,i] * seq[b,j,:] ----
    float o[K*DF];
    #pragma unroll
    for (int i = 0; i < K*DF; ++i) o[i] = 0.f;

    const float4* s4 = reinterpret_cast<const float4*>(seq + (size_t)b * (K*DF));
    #pragma unroll
    for (int j = 0; j < K; ++j) {
        float4 a0 = s4[j*2 + 0];
        float4 a1 = s4[j*2 + 1];
        float srow[DF] = {a0.x, a0.y, a0.z, a0.w, a1.x, a1.y, a1.z, a1.w};
        #pragma unroll
        for (int i = 0; i < K; ++i) {
            const float pv = p[j*K + i];
            #pragma unroll
            for (int d = 0; d < DF; ++d)
                o[i*DF + d] = fmaf(pv, srow[d], o[i*DF + d]);
        }
    }

    // plain cached stores -> L2 write-combines the 12 x 16 B into 3 lines
    float4* o4 = reinterpret_cast<float4*>(out + row * (K*DF));
    #pragma unroll
    for (int q = 0; q < 12; ++q) {
        float4 v;
        v.x = o[q*4+0]; v.y = o[q*4+1]; v.z = o[q*4+2]; v.w = o[q*4+3];
        o4[q] = v;
    }
}

} // namespace

extern "C" void kernel_launch(void* const* d_in, const int* in_sizes, int n_in,
                              void* d_out, int out_size, void* d_ws, size_t ws_size,
                              hipStream_t stream) {
    const float* latent = (const float*)d_in[0];
    const float* seq    = (const float*)d_in[1];
    const float* noise  = (const float*)d_in[2];
    const float* W_sink = (const float*)d_in[3];
    const float* b_sink = (const float*)d_in[4];
    const float* W_mask = (const float*)d_in[5];
    const float* b_mask = (const float*)d_in[6];
    float* out      = (float*)d_out;
    float* stopping = out + (size_t)M * K * DF;

    fused_kernel<<<M / 256, 256, 0, stream>>>(latent, seq, noise,
                                              W_sink, b_sink, W_mask, b_mask,
                                              out, stopping);
}

// Round 12
// 85.881 us; speedup vs baseline: 3.7783x; 1.2242x over previous
//
#include <hip/hip_runtime.h>

namespace {

constexpr int K     = 6;
constexpr int KK    = 36;   // K*K
constexpr int DF    = 8;    // D_FEAT
constexpr int DLAT  = 16;
constexpr int NS    = 5;
constexpr int B     = 131072;
constexpr int M     = NS * B;
constexpr float EPS = 1e-20f;

typedef float f32x4 __attribute__((ext_vector_type(4)));

// grid = 2560 blocks of 256; bid -> (s = bid%5, bc = bid/5): 5 same-bc blocks
// are dispatch-adjacent (latent/seq L3-hot), wave rows contiguous.
// Inputs: plain CACHED loads (L3 retains the 130 MB read-set across replays —
// NT loads cost +28 us in round 11 by bypassing L3).
// Output: per-wave LDS staging + wave-cooperative NONTEMPORAL stores (64
// lanes x 16 B contiguous = full lines -> no allocation in L3, so the 126 MB
// write stream stops evicting the read-set; round 10 showed per-thread NT
// 16-B stores amplify 3x, hence the LDS transpose to full-line form).
__global__ __launch_bounds__(256) void fused_kernel(
    const float* __restrict__ latent,
    const float* __restrict__ seq,
    const float* __restrict__ noise,
    const float* __restrict__ W_sink,
    const float* __restrict__ b_sink,
    const float* __restrict__ W_mask,
    const float* __restrict__ b_mask,
    float* __restrict__ out,        // [NS*B][48]
    float* __restrict__ stopping)   // [B][6]
{
    // 4 waves x 64 rows x 13 chunks(16B) = 53248 B; pad 12->13 spreads banks
    __shared__ f32x4 obuf[4][64 * 13];

    const int bid = blockIdx.x;
    const int s   = bid % NS;
    const int bc  = bid / NS;
    const int t   = threadIdx.x;
    const int w   = t >> 6;
    const int l   = t & 63;
    const int b   = bc * 256 + t;
    const size_t row = (size_t)s * B + b;

    // ---- noise: per-thread cached float4 loads (wave rows contiguous) ----
    float u[KK];
    {
        const float4* n4 = reinterpret_cast<const float4*>(noise + row * KK);
        #pragma unroll
        for (int q = 0; q < 9; ++q) {
            float4 v = n4[q];
            u[q*4+0] = v.x; u[q*4+1] = v.y; u[q*4+2] = v.z; u[q*4+3] = v.w;
        }
    }

    // ---- latent + sinknet matvec (W/b wave-uniform -> scalar loads) ----
    float lat[DLAT];
    {
        const float4* lat4 = reinterpret_cast<const float4*>(latent + (size_t)b * DLAT);
        #pragma unroll
        for (int k2 = 0; k2 < 4; ++k2) {
            float4 v = lat4[k2];
            lat[k2*4+0] = v.x; lat[k2*4+1] = v.y; lat[k2*4+2] = v.z; lat[k2*4+3] = v.w;
        }
    }

    float ela[KK];
    #pragma unroll
    for (int i = 0; i < KK; ++i) ela[i] = b_sink[i];
    #pragma unroll
    for (int k2 = 0; k2 < DLAT; ++k2) {
        const float lv = lat[k2];
        #pragma unroll
        for (int i = 0; i < KK; ++i)
            ela[i] = fmaf(lv, W_sink[k2*KK + i], ela[i]);
    }

    if (s == 0) {   // masknet once per b
        float v[K];
        #pragma unroll
        for (int i = 0; i < K; ++i) v[i] = b_mask[i];
        #pragma unroll
        for (int k2 = 0; k2 < DLAT; ++k2) {
            const float lv = lat[k2];
            #pragma unroll
            for (int i = 0; i < K; ++i)
                v[i] = fmaf(lv, W_mask[k2*K + i], v[i]);
        }
        float mx = v[0];
        #pragma unroll
        for (int i = 1; i < K; ++i) mx = fmaxf(mx, v[i]);
        float sum = 0.f;
        #pragma unroll
        for (int i = 0; i < K; ++i) { v[i] = __expf(v[i] - mx); sum += v[i]; }
        const float inv = __builtin_amdgcn_rcpf(sum);
        float2* o2 = reinterpret_cast<float2*>(stopping + (size_t)b * K);
        o2[0] = make_float2(v[0]*inv, v[1]*inv);
        o2[1] = make_float2(v[2]*inv, v[3]*inv);
        o2[2] = make_float2(v[4]*inv, v[5]*inv);
    }

    // ---- p = exp(la) * rcp(EPS - log(u+EPS))  (== exp(la + gumbel)) ----
    float p[KK];
    #pragma unroll
    for (int i = 0; i < KK; ++i)
        p[i] = __expf(ela[i]) * __builtin_amdgcn_rcpf(EPS - __logf(u[i] + EPS));

    // ---- 5 Sinkhorn iterations, exp domain (== log-domain logsumexp) ----
    #pragma unroll
    for (int it = 0; it < 5; ++it) {
        #pragma unroll
        for (int i = 0; i < K; ++i) {            // rows (axis=2)
            const float sum = ((p[i*K+0] + p[i*K+1]) + (p[i*K+2] + p[i*K+3]))
                            + (p[i*K+4] + p[i*K+5]);
            const float r = __builtin_amdgcn_rcpf(sum);
            #pragma unroll
            for (int j = 0; j < K; ++j) p[i*K+j] *= r;
        }
        #pragma unroll
        for (int j = 0; j < K; ++j) {            // cols (axis=1)
            const float sum = ((p[0*K+j] + p[1*K+j]) + (p[2*K+j] + p[3*K+j]))
                            + (p[4*K+j] + p[5*K+j]);
            const float r = __builtin_amdgcn_rcpf(sum);
            #pragma unroll
            for (int i = 0; i < K; ++i) p[i*K+j] *= r;
        }
    }

    // ---- ordered[row,i,:] = sum_j P[j,i] * seq[b,j,:] ----
    float o[K*DF];
    #pragma unroll
    for (int i = 0; i < K*DF; ++i) o[i] = 0.f;

    const float4* s4 = reinterpret_cast<const float4*>(seq + (size_t)b * (K*DF));
    #pragma unroll
    for (int j = 0; j < K; ++j) {
        float4 a0 = s4[j*2 + 0];
        float4 a1 = s4[j*2 + 1];
        float srow[DF] = {a0.x, a0.y, a0.z, a0.w, a1.x, a1.y, a1.z, a1.w};
        #pragma unroll
        for (int i = 0; i < K; ++i) {
            const float pv = p[j*K + i];
            #pragma unroll
            for (int d = 0; d < DF; ++d)
                o[i*DF + d] = fmaf(pv, srow[d], o[i*DF + d]);
        }
    }

    // ---- stage row into per-wave LDS (padded stride 13) ----
    #pragma unroll
    for (int q = 0; q < 12; ++q) {
        f32x4 v;
        v.x = o[q*4+0]; v.y = o[q*4+1]; v.z = o[q*4+2]; v.w = o[q*4+3];
        obuf[w][l * 13 + q] = v;
    }
    asm volatile("" ::: "memory");   // DS pipe is per-wave in-order (validated r11)

    // ---- wave-cooperative NT store: 12 instrs x 1 KB contiguous ----
    f32x4* outv = reinterpret_cast<f32x4*>(out)
                + ((size_t)s * B + (size_t)bc * 256 + (size_t)w * 64) * 12;
    #pragma unroll
    for (int q = 0; q < 12; ++q) {
        const int c   = q * 64 + l;          // chunk index in [0,768)
        const int r   = c / 12;              // source row in wave
        const int off = c - r * 12;          // chunk within row
        __builtin_nontemporal_store(obuf[w][r * 13 + off], &outv[c]);
    }
}

} // namespace

extern "C" void kernel_launch(void* const* d_in, const int* in_sizes, int n_in,
                              void* d_out, int out_size, void* d_ws, size_t ws_size,
                              hipStream_t stream) {
    const float* latent = (const float*)d_in[0];
    const float* seq    = (const float*)d_in[1];
    const float* noise  = (const float*)d_in[2];
    const float* W_sink = (const float*)d_in[3];
    const float* b_sink = (const float*)d_in[4];
    const float* W_mask = (const float*)d_in[5];
    const float* b_mask = (const float*)d_in[6];
    float* out      = (float*)d_out;
    float* stopping = out + (size_t)M * K * DF;

    fused_kernel<<<M / 256, 256, 0, stream>>>(latent, seq, noise,
                                              W_sink, b_sink, W_mask, b_mask,
                                              out, stopping);
}